// Round 9
// baseline (351.443 us; speedup 1.0000x reference)
//
#include <hip/hip_runtime.h>
#include <math.h>
#include <float.h>

// VQVAE forward, MI355X. Round 9: R8 skeleton + BK=64 K-loops (half the
// barriers; per-iter glds drain amortized 2x; LDS 48-64KB is free since grids
// already cap at 2 blocks/CU). Encoder/argmin bf16x3, decoder bf16x2.

typedef __attribute__((ext_vector_type(8))) short short8;      // MFMA A/B frag
typedef __attribute__((ext_vector_type(4))) float floatx4;     // MFMA C/D frag
typedef __attribute__((ext_vector_type(4))) unsigned short ushort4v;

__device__ __forceinline__ unsigned short f2bf(float f) {
  union { float f; unsigned u; } v; v.f = f;
  unsigned u = v.u;
  return (unsigned short)((u + 0x7FFFu + ((u >> 16) & 1u)) >> 16);
}
__device__ __forceinline__ float bf2f(unsigned short s) {
  union { unsigned u; float f; } v; v.u = ((unsigned)s) << 16;
  return v.f;
}

__device__ __forceinline__ void glds16(const void* g, void* l) {
  __builtin_amdgcn_global_load_lds(
      (const __attribute__((address_space(1))) unsigned int*)g,
      (__attribute__((address_space(3))) unsigned int*)l, 16, 0, 0);
}

__device__ __forceinline__ unsigned packkey(float d, int c) {
  unsigned b = __float_as_uint(d);
  b = (b & 0x80000000u) ? ~b : (b | 0x80000000u);
  return (b & 0xFFFFF800u) | (unsigned)c;
}
__device__ __forceinline__ void ins3(unsigned k, unsigned& v1, unsigned& v2,
                                     unsigned& v3) {
  unsigned t1 = min(v1, k), c1 = max(v1, k);
  unsigned t2 = min(v2, c1), c2 = max(v2, c1);
  v1 = t1; v2 = t2; v3 = min(v3, c2);
}

__global__ __launch_bounds__(256) void conv_pad(
    const float* __restrict__ src, unsigned short* __restrict__ hi,
    unsigned short* __restrict__ mid, int R, int C, int Rp, int Cp) {
  int t = blockIdx.x * 256 + threadIdx.x;
  if (t >= Rp * Cp) return;
  int r = t / Cp, c = t - r * Cp;
  float v = (r < R && c < C) ? src[(long)r * C + c] : 0.f;
  unsigned short h = f2bf(v);
  hi[t] = h;
  mid[t] = f2bf(v - bf2f(h));
}

__global__ __launch_bounds__(256) void emb_norm(const float* __restrict__ emb,
                                                float* __restrict__ enorm) {
  const int gtid = blockIdx.x * 256 + threadIdx.x;
  const int j = gtid >> 6;
  const int lane = threadIdx.x & 63;
  float4 v = *(const float4*)(emb + (long)j * 256 + (lane << 2));
  float s = v.x * v.x + v.y * v.y + v.z * v.z + v.w * v.w;
#pragma unroll
  for (int off = 1; off < 64; off <<= 1) s += __shfl_xor(s, off, 64);
  if (lane == 0) enorm[j] = s;
}

#define BK 64  // shorts per LDS row (128B); 2 MFMA K-steps per tile

enum { EPI_NONE = 0, EPI_RELU = 1, EPI_SIGMOID = 2 };
// OMODE: 0 = fp32 out, 1 = hi/mid split out, 3 = hi-only bf16 out
// NPROD: 3 = ah*bh + ah*bm + am*bh; 2 = ah*bh + ah*bm (A hi-only)
// Wave grid 2x2; wave tile (TMW*16) x (TNW*16); BM = TMW*32, BN = TNW*32.

template <int EPI, bool INDIRECT, bool ASPLIT, int OMODE, int TMW, int TNW, int NPROD>
__global__ __launch_bounds__(256, 2) void mfma_gemm(
    const float* __restrict__ Af, const unsigned short* __restrict__ Ahg,
    const unsigned short* __restrict__ Amg, const unsigned short* __restrict__ Bhi,
    const unsigned short* __restrict__ Bmid, const float* __restrict__ bias,
    float* __restrict__ Cf, unsigned short* __restrict__ Ohi,
    unsigned short* __restrict__ Omid, const int* __restrict__ aidx,
    int M, int N, int K, int Nreal) {
  constexpr int BM = TMW * 32;
  constexpr int BN = TNW * 32;
  constexpr int AG = BM / 32;     // 8-row glds groups per wave per A array
  constexpr int BG = BN / 32;     // per B array
  constexpr int ACELL = BM / 16;  // fp32-A staging cells (float4 each)
  __shared__ __align__(16) unsigned short Ah[BM][BK];
  __shared__ __align__(16) unsigned short Am[(NPROD == 3) ? BM : 1][BK];
  __shared__ __align__(16) unsigned short Bh[BN][BK], Bm[BN][BK];

  const int tid = threadIdx.x, lane = tid & 63, wave = tid >> 6;
  const int wm = wave >> 1, wn = wave & 1;
  const int row0 = blockIdx.y * BM, col0 = blockIdx.x * BN;
  const int grow = lane >> 3;            // row within 8-row group
  const int kshort = (lane & 7) * 8;     // 16B granule within 128B row

  const unsigned short *aH[AG], *aM2[AG], *bH[BG], *bM2[BG];
  const float* aF[ACELL];
  if (ASPLIT) {
#pragma unroll
    for (int j = 0; j < AG; j++) {
      const int rl = (wave * AG + j) * 8 + grow;
      const long ar = INDIRECT ? (long)aidx[row0 + rl] : (long)(row0 + rl);
      aH[j] = Ahg + ar * K + kshort;
      if (NPROD == 3) aM2[j] = Amg + ar * K + kshort;
    }
  } else {
#pragma unroll
    for (int i = 0; i < ACELL; i++)
      aF[i] = Af + (long)(row0 + i * 16 + (tid >> 4)) * K + (tid & 15) * 4;
  }
#pragma unroll
  for (int j = 0; j < BG; j++) {
    const int rl = (wave * BG + j) * 8 + grow;
    bH[j] = Bhi + (long)(col0 + rl) * K + kshort;
    bM2[j] = Bmid + (long)(col0 + rl) * K + kshort;
  }

  floatx4 acc[TMW][TNW];
#pragma unroll
  for (int i = 0; i < TMW; i++)
#pragma unroll
    for (int j = 0; j < TNW; j++) acc[i][j] = (floatx4)0.f;

  for (int k0 = 0; k0 < K; k0 += BK) {
    float4 areg[ACELL];
    if (!ASPLIT) {
#pragma unroll
      for (int i = 0; i < ACELL; i++) areg[i] = *(const float4*)(aF[i] + k0);
    }
    __syncthreads();  // prev-iter LDS reads complete
#pragma unroll
    for (int j = 0; j < BG; j++) {
      const int slot = wave * BG + j;  // 8-row group -> 1KB LDS
      glds16(bH[j] + k0, &Bh[0][0] + slot * 512);
      glds16(bM2[j] + k0, &Bm[0][0] + slot * 512);
    }
    if (ASPLIT) {
#pragma unroll
      for (int j = 0; j < AG; j++) {
        const int slot = wave * AG + j;
        glds16(aH[j] + k0, &Ah[0][0] + slot * 512);
        if (NPROD == 3) glds16(aM2[j] + k0, &Am[0][0] + slot * 512);
      }
    } else {
#pragma unroll
      for (int i = 0; i < ACELL; i++) {
        const int r = i * 16 + (tid >> 4), q4 = (tid & 15) * 4;
        ushort4v h, m;
        h.x = f2bf(areg[i].x); m.x = f2bf(areg[i].x - bf2f(h.x));
        h.y = f2bf(areg[i].y); m.y = f2bf(areg[i].y - bf2f(h.y));
        h.z = f2bf(areg[i].z); m.z = f2bf(areg[i].z - bf2f(h.z));
        h.w = f2bf(areg[i].w); m.w = f2bf(areg[i].w - bf2f(h.w));
        *(ushort4v*)&Ah[r][q4] = h;
        *(ushort4v*)&Am[r][q4] = m;
      }
    }
    __syncthreads();  // staging published

#pragma unroll
    for (int half = 0; half < 2; half++) {
      const int kk = half * 32 + (lane >> 4) * 8;
      short8 ah[TMW], am[TMW];
#pragma unroll
      for (int tm = 0; tm < TMW; tm++) {
        const int rr = wm * (TMW * 16) + tm * 16 + (lane & 15);
        ah[tm] = *(const short8*)&Ah[rr][kk];
        if (NPROD == 3) am[tm] = *(const short8*)&Am[rr][kk];
      }
#pragma unroll
      for (int tn = 0; tn < TNW; tn++) {
        const int rr = wn * (TNW * 16) + tn * 16 + (lane & 15);
        short8 bh = *(const short8*)&Bh[rr][kk];
        short8 bm = *(const short8*)&Bm[rr][kk];
#pragma unroll
        for (int tm = 0; tm < TMW; tm++) {
          acc[tm][tn] = __builtin_amdgcn_mfma_f32_16x16x32_bf16(ah[tm], bh, acc[tm][tn], 0, 0, 0);
          acc[tm][tn] = __builtin_amdgcn_mfma_f32_16x16x32_bf16(ah[tm], bm, acc[tm][tn], 0, 0, 0);
          if (NPROD == 3)
            acc[tm][tn] = __builtin_amdgcn_mfma_f32_16x16x32_bf16(am[tm], bh, acc[tm][tn], 0, 0, 0);
        }
      }
    }
  }

  // C/D layout: col = lane&15, row = (lane>>4)*4 + reg
  const int qd = lane >> 4, ln = lane & 15;
#pragma unroll
  for (int tn = 0; tn < TNW; tn++) {
    const int c = col0 + wn * (TNW * 16) + tn * 16 + ln;
    const float bb = (c < Nreal) ? bias[c] : 0.f;
#pragma unroll
    for (int tm = 0; tm < TMW; tm++) {
#pragma unroll
      for (int reg = 0; reg < 4; reg++) {
        const int r = row0 + wm * (TMW * 16) + tm * 16 + qd * 4 + reg;
        float v = acc[tm][tn][reg] + bb;
        if (EPI == EPI_RELU) v = fmaxf(v, 0.f);
        if (EPI == EPI_SIGMOID) v = 1.f / (1.f + __expf(-v));
        if (OMODE == 0) {
          Cf[(long)r * N + c] = v;
        } else if (OMODE == 1) {
          unsigned short h = f2bf(v);
          Ohi[(long)r * N + c] = h;
          Omid[(long)r * N + c] = f2bf(v - bf2f(h));
        } else {  // OMODE == 3: hi only
          Ohi[(long)r * N + c] = f2bf(v);
        }
      }
    }
  }
}

// dist candidates: grid (M/128 rows, 4 groups); block sweeps 512 cols in 4
// chunks of 128; BK=64 (4 iters/chunk). XCD-affine (grid-x = row-block).
__global__ __launch_bounds__(256, 2) void dist_topk(
    const unsigned short* __restrict__ Zh, const unsigned short* __restrict__ Zm,
    const unsigned short* __restrict__ Eh, const unsigned short* __restrict__ Em,
    const float* __restrict__ enorm, int* __restrict__ pidx, int M) {
  const int K = 256;
  __shared__ __align__(16) unsigned short Ah[128][BK], Am[128][BK];
  __shared__ __align__(16) unsigned short Bh[128][BK], Bm[128][BK];
  __shared__ unsigned r1s[2][128], r2s[2][128], r3s[2][128];

  const int tid = threadIdx.x, lane = tid & 63, wave = tid >> 6;
  const int wm = wave >> 1, wn = wave & 1;
  const int row0 = blockIdx.x * 128;
  const int col_base = blockIdx.y * 512;
  const int grow = lane >> 3;
  const int kshort = (lane & 7) * 8;

  const unsigned short *aH[4], *aM2[4];
  int rlj[4];
#pragma unroll
  for (int j = 0; j < 4; j++) {
    rlj[j] = (wave * 4 + j) * 8 + grow;
    aH[j] = Zh + (long)(row0 + rlj[j]) * K + kshort;
    aM2[j] = Zm + (long)(row0 + rlj[j]) * K + kshort;
  }

  unsigned k1[16], k2[16], k3[16];
#pragma unroll
  for (int s = 0; s < 16; s++) { k1[s] = 0xFFFFFFFFu; k2[s] = 0xFFFFFFFFu; k3[s] = 0xFFFFFFFFu; }

  for (int ch = 0; ch < 4; ch++) {
    const int col0 = col_base + ch * 128;
    floatx4 acc[4][4];
#pragma unroll
    for (int i = 0; i < 4; i++)
#pragma unroll
      for (int j = 0; j < 4; j++) acc[i][j] = (floatx4)0.f;

    for (int k0 = 0; k0 < K; k0 += BK) {
      __syncthreads();
#pragma unroll
      for (int j = 0; j < 4; j++) {
        const int slot = wave * 4 + j;
        glds16(aH[j] + k0, &Ah[0][0] + slot * 512);
        glds16(aM2[j] + k0, &Am[0][0] + slot * 512);
        glds16(Eh + (long)(col0 + rlj[j]) * K + kshort + k0, &Bh[0][0] + slot * 512);
        glds16(Em + (long)(col0 + rlj[j]) * K + kshort + k0, &Bm[0][0] + slot * 512);
      }
      __syncthreads();

#pragma unroll
      for (int half = 0; half < 2; half++) {
        const int kk = half * 32 + (lane >> 4) * 8;
        short8 ah[4], am[4];
#pragma unroll
        for (int tm = 0; tm < 4; tm++) {
          const int rr = wm * 64 + tm * 16 + (lane & 15);
          ah[tm] = *(const short8*)&Ah[rr][kk];
          am[tm] = *(const short8*)&Am[rr][kk];
        }
#pragma unroll
        for (int tn = 0; tn < 4; tn++) {
          const int rr = wn * 64 + tn * 16 + (lane & 15);
          short8 bh = *(const short8*)&Bh[rr][kk];
          short8 bm = *(const short8*)&Bm[rr][kk];
#pragma unroll
          for (int tm = 0; tm < 4; tm++) {
            acc[tm][tn] = __builtin_amdgcn_mfma_f32_16x16x32_bf16(ah[tm], bh, acc[tm][tn], 0, 0, 0);
            acc[tm][tn] = __builtin_amdgcn_mfma_f32_16x16x32_bf16(ah[tm], bm, acc[tm][tn], 0, 0, 0);
            acc[tm][tn] = __builtin_amdgcn_mfma_f32_16x16x32_bf16(am[tm], bh, acc[tm][tn], 0, 0, 0);
          }
        }
      }
    }

#pragma unroll
    for (int tn = 0; tn < 4; tn++) {
      const int c = col0 + wn * 64 + tn * 16 + (lane & 15);
      const float en = enorm[c];
#pragma unroll
      for (int tm = 0; tm < 4; tm++)
#pragma unroll
        for (int reg = 0; reg < 4; reg++) {
          float d = en - 2.f * acc[tm][tn][reg];
          ins3(packkey(d, c), k1[tm * 4 + reg], k2[tm * 4 + reg], k3[tm * 4 + reg]);
        }
    }
  }

#pragma unroll
  for (int s = 0; s < 16; s++) {
#pragma unroll
    for (int off = 1; off < 16; off <<= 1) {
      unsigned o1 = __shfl_xor(k1[s], off, 64);
      unsigned o2 = __shfl_xor(k2[s], off, 64);
      unsigned o3 = __shfl_xor(k3[s], off, 64);
      ins3(o1, k1[s], k2[s], k3[s]);
      ins3(o2, k1[s], k2[s], k3[s]);
      ins3(o3, k1[s], k2[s], k3[s]);
    }
  }
  if ((lane & 15) == 0) {
#pragma unroll
    for (int s = 0; s < 16; s++) {
      int rl = wm * 64 + (s >> 2) * 16 + (lane >> 4) * 4 + (s & 3);
      r1s[wn][rl] = k1[s]; r2s[wn][rl] = k2[s]; r3s[wn][rl] = k3[s];
    }
  }
  __syncthreads();
  if (tid < 128) {
    unsigned v1 = r1s[0][tid], v2 = r2s[0][tid], v3 = r3s[0][tid];
    ins3(r1s[1][tid], v1, v2, v3);
    ins3(r2s[1][tid], v1, v2, v3);
    ins3(r3s[1][tid], v1, v2, v3);
    const long base = ((long)blockIdx.y * M + (row0 + tid)) * 4;
    pidx[base + 0] = (int)(v1 & 0x7FFu);
    pidx[base + 1] = (int)(v2 & 0x7FFu);
    pidx[base + 2] = (int)(v3 & 0x7FFu);
  }
}

// exact fp32 rescore of 12 candidates/row; z = hi + mid. One wave per row.
__global__ __launch_bounds__(256) void rescore(
    const unsigned short* __restrict__ zh, const unsigned short* __restrict__ zm,
    const float* __restrict__ emb, const float* __restrict__ enorm,
    const int* __restrict__ pidx, int* __restrict__ idx, int M) {
  const int wave = threadIdx.x >> 6, lane = threadIdx.x & 63;
  const int r = blockIdx.x * 4 + wave;
  ushort4v hz = *(const ushort4v*)(zh + (long)r * 256 + lane * 4);
  ushort4v mz = *(const ushort4v*)(zm + (long)r * 256 + lane * 4);
  float4 zv;
  zv.x = bf2f(hz.x) + bf2f(mz.x);
  zv.y = bf2f(hz.y) + bf2f(mz.y);
  zv.z = bf2f(hz.z) + bf2f(mz.z);
  zv.w = bf2f(hz.w) + bf2f(mz.w);
  float best = FLT_MAX;
  int bi = 0x7fffffff;
  for (int g = 0; g < 4; g++) {
#pragma unroll
    for (int s = 0; s < 3; s++) {
      const int j = pidx[((long)g * M + r) * 4 + s];
      float4 ev = *(const float4*)(emb + (long)j * 256 + lane * 4);
      float t = zv.x * ev.x + zv.y * ev.y + zv.z * ev.z + zv.w * ev.w;
#pragma unroll
      for (int off = 1; off < 64; off <<= 1) t += __shfl_xor(t, off, 64);
      const float d = enorm[j] - 2.f * t;
      if (d < best || (d == best && j < bi)) { best = d; bi = j; }
    }
  }
  if (lane == 0) idx[r] = bi;
}

extern "C" void kernel_launch(void* const* d_in, const int* in_sizes, int n_in,
                              void* d_out, int out_size, void* d_ws, size_t ws_size,
                              hipStream_t stream) {
  const float* x   = (const float*)d_in[0];
  const float* W1  = (const float*)d_in[1];
  const float* b1  = (const float*)d_in[2];
  const float* W2  = (const float*)d_in[3];
  const float* b2  = (const float*)d_in[4];
  const float* W3  = (const float*)d_in[5];
  const float* b3  = (const float*)d_in[6];
  const float* W4  = (const float*)d_in[7];
  const float* b4  = (const float*)d_in[8];
  const float* emb = (const float*)d_in[9];
  float* out = (float*)d_out;

  const int BZ = 16384, IN = 1024, H = 400, Hp = 512, D = 256, NE = 2048;

  char* ws = (char*)d_ws;
  size_t off = 0;
  auto alloc = [&](size_t bytes) {
    void* p = ws + off;
    off += (bytes + 255) & ~(size_t)255;
    return p;
  };
  unsigned short* w1h = (unsigned short*)alloc((size_t)Hp * IN * 2);
  unsigned short* w1m = (unsigned short*)alloc((size_t)Hp * IN * 2);
  unsigned short* w2h = (unsigned short*)alloc((size_t)D * Hp * 2);
  unsigned short* w2m = (unsigned short*)alloc((size_t)D * Hp * 2);
  unsigned short* w3h = (unsigned short*)alloc((size_t)Hp * D * 2);
  unsigned short* w3m = (unsigned short*)alloc((size_t)Hp * D * 2);
  unsigned short* w4h = (unsigned short*)alloc((size_t)IN * Hp * 2);
  unsigned short* w4m = (unsigned short*)alloc((size_t)IN * Hp * 2);
  unsigned short* eh  = (unsigned short*)alloc((size_t)NE * D * 2);
  unsigned short* em  = (unsigned short*)alloc((size_t)NE * D * 2);
  float* enorm = (float*)alloc((size_t)NE * 4);
  unsigned short* h1h = (unsigned short*)alloc((size_t)BZ * Hp * 2);  // 16MB
  unsigned short* h1m = (unsigned short*)alloc((size_t)BZ * Hp * 2);  // 16MB
  unsigned short* zh  = (unsigned short*)alloc((size_t)BZ * D * 2);   // 8MB
  unsigned short* zm  = (unsigned short*)alloc((size_t)BZ * D * 2);   // 8MB
  // aliases (lifetimes disjoint on the sequential stream):
  int* pidx = (int*)h1h;                       // h1 dead after GEMM2 (1MB used)
  int* idx  = ((int*)h1h) + (size_t)4 * BZ * 4;
  unsigned short* h3h = h1m;                   // h1m dead after GEMM2 (16MB)

  conv_pad<<<dim3((Hp * IN + 255) / 256), dim3(256), 0, stream>>>(W1, w1h, w1m, H, IN, Hp, IN);
  conv_pad<<<dim3((D * Hp + 255) / 256), dim3(256), 0, stream>>>(W2, w2h, w2m, D, H, D, Hp);
  conv_pad<<<dim3((Hp * D + 255) / 256), dim3(256), 0, stream>>>(W3, w3h, w3m, H, D, Hp, D);
  conv_pad<<<dim3((IN * Hp + 255) / 256), dim3(256), 0, stream>>>(W4, w4h, w4m, IN, H, IN, Hp);
  conv_pad<<<dim3((NE * D + 255) / 256), dim3(256), 0, stream>>>(emb, eh, em, NE, D, NE, D);
  emb_norm<<<dim3(NE * 64 / 256), dim3(256), 0, stream>>>(emb, enorm);

  // h1 = relu(x @ W1^T + b1) -> hi/mid [BZ][512]   (bf16x3, 128x128, 512 blocks)
  mfma_gemm<EPI_RELU, false, false, 1, 4, 4, 3><<<dim3(Hp / 128, BZ / 128), dim3(256), 0, stream>>>(
      x, nullptr, nullptr, w1h, w1m, b1, nullptr, h1h, h1m, nullptr, BZ, Hp, IN, H);
  // z = h1 @ W2^T + b2 -> hi/mid [BZ][256]   (bf16x3, 64x128, 512 blocks)
  mfma_gemm<EPI_NONE, false, true, 1, 2, 4, 3><<<dim3(D / 128, BZ / 64), dim3(256), 0, stream>>>(
      nullptr, h1h, h1m, w2h, w2m, b2, nullptr, zh, zm, nullptr, BZ, D, Hp, D);
  // dist candidates: top-3 per 512-col group (XCD-affine grid), bf16x3
  dist_topk<<<dim3(BZ / 128, 4), dim3(256), 0, stream>>>(zh, zm, eh, em, enorm, pidx, BZ);
  // exact fp32 rescore of 12 -> idx
  rescore<<<dim3(BZ / 4), dim3(256), 0, stream>>>(zh, zm, emb, enorm, pidx, idx, BZ);
  // h3 = relu(emb[idx] @ W3^T + b3) -> bf16 hi only  (bf16x2 decoder, 512 blocks)
  mfma_gemm<EPI_RELU, true, true, 3, 4, 4, 2><<<dim3(Hp / 128, BZ / 128), dim3(256), 0, stream>>>(
      nullptr, eh, nullptr, w3h, w3m, b3, nullptr, h3h, nullptr, idx, BZ, Hp, D, H);
  // out = sigmoid(h3 @ W4^T + b4) -> fp32 [BZ][1024]  (bf16x2, 1024 blocks)
  mfma_gemm<EPI_SIGMOID, false, true, 0, 4, 4, 2><<<dim3(IN / 128, BZ / 128), dim3(256), 0, stream>>>(
      nullptr, h3h, nullptr, w4h, w4m, b4, out, nullptr, nullptr, nullptr, BZ, IN, Hp, IN);
}

// Round 10
// 335.090 us; speedup vs baseline: 1.0488x; 1.0488x over previous
//
#include <hip/hip_runtime.h>
#include <math.h>
#include <float.h>

// VQVAE forward, MI355X. Round 10: R8 skeleton (best: 349us, BK=32) with all
// prep work (5x weight/codebook hi/mid conversion + emb norms) fused into ONE
// kernel to remove ~5 small-dispatch overheads. Encoder/argmin bf16x3 (hi/mid
// RNE split = fp32-grade), decoder bf16x2. dist: XCD-affine top-3 per 512-col
// group + exact fp32 rescore of 12 candidates.

typedef __attribute__((ext_vector_type(8))) short short8;      // MFMA A/B frag
typedef __attribute__((ext_vector_type(4))) float floatx4;     // MFMA C/D frag
typedef __attribute__((ext_vector_type(4))) unsigned short ushort4v;

__device__ __forceinline__ unsigned short f2bf(float f) {
  union { float f; unsigned u; } v; v.f = f;
  unsigned u = v.u;
  return (unsigned short)((u + 0x7FFFu + ((u >> 16) & 1u)) >> 16);
}
__device__ __forceinline__ float bf2f(unsigned short s) {
  union { unsigned u; float f; } v; v.u = ((unsigned)s) << 16;
  return v.f;
}

__device__ __forceinline__ void glds16(const void* g, void* l) {
  __builtin_amdgcn_global_load_lds(
      (const __attribute__((address_space(1))) unsigned int*)g,
      (__attribute__((address_space(3))) unsigned int*)l, 16, 0, 0);
}

__device__ __forceinline__ unsigned packkey(float d, int c) {
  unsigned b = __float_as_uint(d);
  b = (b & 0x80000000u) ? ~b : (b | 0x80000000u);
  return (b & 0xFFFFF800u) | (unsigned)c;
}
__device__ __forceinline__ void ins3(unsigned k, unsigned& v1, unsigned& v2,
                                     unsigned& v3) {
  unsigned t1 = min(v1, k), c1 = max(v1, k);
  unsigned t2 = min(v2, c1), c2 = max(v2, c1);
  v1 = t1; v2 = t2; v3 = min(v3, c2);
}

// one fp32->hi/mid padded conversion element; Cp compile-time (shifts)
template <int Cp>
__device__ __forceinline__ void conv_one(
    const float* __restrict__ src, unsigned short* __restrict__ hi,
    unsigned short* __restrict__ mid, int R, int C, int b) {
  const int t = b * 256 + (int)threadIdx.x;
  const int r = t / Cp, c = t & (Cp - 1);
  float v = (r < R && c < C) ? src[(long)r * C + c] : 0.f;
  unsigned short h = f2bf(v);
  hi[t] = h;
  mid[t] = f2bf(v - bf2f(h));
}

// fused prep: regions (block counts): W1 2048 | W2 512 | W3 512 | W4 2048 |
// emb 2048 | enorm 512. Grid = 7680 blocks.
__global__ __launch_bounds__(256) void prep(
    const float* __restrict__ W1, unsigned short* __restrict__ w1h, unsigned short* __restrict__ w1m,
    const float* __restrict__ W2, unsigned short* __restrict__ w2h, unsigned short* __restrict__ w2m,
    const float* __restrict__ W3, unsigned short* __restrict__ w3h, unsigned short* __restrict__ w3m,
    const float* __restrict__ W4, unsigned short* __restrict__ w4h, unsigned short* __restrict__ w4m,
    const float* __restrict__ emb, unsigned short* __restrict__ eh, unsigned short* __restrict__ em,
    float* __restrict__ enorm) {
  int b = blockIdx.x;
  if (b < 2048) {                       // W1: 400x1024 -> 512x1024
    conv_one<1024>(W1, w1h, w1m, 400, 1024, b);
  } else if (b < 2560) {                // W2: 256x400 -> 256x512
    conv_one<512>(W2, w2h, w2m, 256, 400, b - 2048);
  } else if (b < 3072) {                // W3: 400x256 -> 512x256
    conv_one<256>(W3, w3h, w3m, 400, 256, b - 2560);
  } else if (b < 5120) {                // W4: 1024x400 -> 1024x512
    conv_one<512>(W4, w4h, w4m, 1024, 400, b - 3072);
  } else if (b < 7168) {                // emb: 2048x256 -> 2048x256
    conv_one<256>(emb, eh, em, 2048, 256, b - 5120);
  } else {                              // enorm: 4 rows/block, 1 wave/row
    const int gtid = (b - 7168) * 256 + (int)threadIdx.x;
    const int j = gtid >> 6;
    const int lane = threadIdx.x & 63;
    float4 v = *(const float4*)(emb + (long)j * 256 + (lane << 2));
    float s = v.x * v.x + v.y * v.y + v.z * v.z + v.w * v.w;
#pragma unroll
    for (int off = 1; off < 64; off <<= 1) s += __shfl_xor(s, off, 64);
    if (lane == 0) enorm[j] = s;
  }
}

#define BK 32

enum { EPI_NONE = 0, EPI_RELU = 1, EPI_SIGMOID = 2 };
// OMODE: 0 = fp32 out, 1 = hi/mid split out, 3 = hi-only bf16 out
// NPROD: 3 = ah*bh + ah*bm + am*bh (fp32-grade); 2 = ah*bh + ah*bm (A hi-only)
// Wave grid 2x2; wave tile (TMW*16) x (TNW*16); BM = TMW*32, BN = TNW*32.

template <int EPI, bool INDIRECT, bool ASPLIT, int OMODE, int TMW, int TNW, int NPROD>
__global__ __launch_bounds__(256, 3) void mfma_gemm(
    const float* __restrict__ Af, const unsigned short* __restrict__ Ahg,
    const unsigned short* __restrict__ Amg, const unsigned short* __restrict__ Bhi,
    const unsigned short* __restrict__ Bmid, const float* __restrict__ bias,
    float* __restrict__ Cf, unsigned short* __restrict__ Ohi,
    unsigned short* __restrict__ Omid, const int* __restrict__ aidx,
    int M, int N, int K, int Nreal) {
  constexpr int BM = TMW * 32;
  constexpr int BN = TNW * 32;
  constexpr int ASW = BM / 64;    // A 16-row slots per wave per array
  constexpr int BSW = BN / 64;    // B 16-row slots per wave per array
  constexpr int ACELL = BM / 32;  // fp32-A staging cells
  __shared__ __align__(16) unsigned short Ah[BM][BK];
  __shared__ __align__(16) unsigned short Am[(NPROD == 3) ? BM : 1][BK];
  __shared__ __align__(16) unsigned short Bh[BN][BK], Bm[BN][BK];

  const int tid = threadIdx.x, lane = tid & 63, wave = tid >> 6;
  const int wm = wave >> 1, wn = wave & 1;
  const int row0 = blockIdx.y * BM, col0 = blockIdx.x * BN;
  const int kshort = (lane & 3) * 8;

  const unsigned short *aH[ASW], *aM2[ASW], *bH[BSW], *bM2[BSW];
  const float* aF[ACELL];
  if (ASPLIT) {
#pragma unroll
    for (int j = 0; j < ASW; j++) {
      const int rl = (wave * ASW + j) * 16 + (lane >> 2);
      const long ar = INDIRECT ? (long)aidx[row0 + rl] : (long)(row0 + rl);
      aH[j] = Ahg + ar * K + kshort;
      if (NPROD == 3) aM2[j] = Amg + ar * K + kshort;
    }
  } else {
#pragma unroll
    for (int i = 0; i < ACELL; i++)
      aF[i] = Af + (long)(row0 + i * 32 + (tid >> 3)) * K + (tid & 7) * 4;
  }
#pragma unroll
  for (int j = 0; j < BSW; j++) {
    const int rl = (wave * BSW + j) * 16 + (lane >> 2);
    bH[j] = Bhi + (long)(col0 + rl) * K + kshort;
    bM2[j] = Bmid + (long)(col0 + rl) * K + kshort;
  }

  floatx4 acc[TMW][TNW];
#pragma unroll
  for (int i = 0; i < TMW; i++)
#pragma unroll
    for (int j = 0; j < TNW; j++) acc[i][j] = (floatx4)0.f;

  for (int k0 = 0; k0 < K; k0 += BK) {
    float4 areg[ACELL];
    if (!ASPLIT) {
#pragma unroll
      for (int i = 0; i < ACELL; i++) areg[i] = *(const float4*)(aF[i] + k0);
    }
    __syncthreads();  // prev-iter LDS reads complete
#pragma unroll
    for (int j = 0; j < BSW; j++) {
      const int slot = wave * BSW + j;
      glds16(bH[j] + k0, &Bh[0][0] + slot * 512);
      glds16(bM2[j] + k0, &Bm[0][0] + slot * 512);
    }
    if (ASPLIT) {
#pragma unroll
      for (int j = 0; j < ASW; j++) {
        const int slot = wave * ASW + j;
        glds16(aH[j] + k0, &Ah[0][0] + slot * 512);
        if (NPROD == 3) glds16(aM2[j] + k0, &Am[0][0] + slot * 512);
      }
    } else {
#pragma unroll
      for (int i = 0; i < ACELL; i++) {
        const int r = i * 32 + (tid >> 3), q4 = (tid & 7) * 4;
        ushort4v h, m;
        h.x = f2bf(areg[i].x); m.x = f2bf(areg[i].x - bf2f(h.x));
        h.y = f2bf(areg[i].y); m.y = f2bf(areg[i].y - bf2f(h.y));
        h.z = f2bf(areg[i].z); m.z = f2bf(areg[i].z - bf2f(h.z));
        h.w = f2bf(areg[i].w); m.w = f2bf(areg[i].w - bf2f(h.w));
        *(ushort4v*)&Ah[r][q4] = h;
        *(ushort4v*)&Am[r][q4] = m;
      }
    }
    __syncthreads();  // staging published

    short8 ah[TMW], am[TMW];
#pragma unroll
    for (int tm = 0; tm < TMW; tm++) {
      const int rr = wm * (TMW * 16) + tm * 16 + (lane & 15);
      const int kk = (lane >> 4) * 8;
      ah[tm] = *(const short8*)&Ah[rr][kk];
      if (NPROD == 3) am[tm] = *(const short8*)&Am[rr][kk];
    }
#pragma unroll
    for (int tn = 0; tn < TNW; tn++) {
      const int rr = wn * (TNW * 16) + tn * 16 + (lane & 15);
      const int kk = (lane >> 4) * 8;
      short8 bh = *(const short8*)&Bh[rr][kk];
      short8 bm = *(const short8*)&Bm[rr][kk];
#pragma unroll
      for (int tm = 0; tm < TMW; tm++) {
        acc[tm][tn] = __builtin_amdgcn_mfma_f32_16x16x32_bf16(ah[tm], bh, acc[tm][tn], 0, 0, 0);
        acc[tm][tn] = __builtin_amdgcn_mfma_f32_16x16x32_bf16(ah[tm], bm, acc[tm][tn], 0, 0, 0);
        if (NPROD == 3)
          acc[tm][tn] = __builtin_amdgcn_mfma_f32_16x16x32_bf16(am[tm], bh, acc[tm][tn], 0, 0, 0);
      }
    }
  }

  // C/D layout: col = lane&15, row = (lane>>4)*4 + reg
  const int qd = lane >> 4, ln = lane & 15;
#pragma unroll
  for (int tn = 0; tn < TNW; tn++) {
    const int c = col0 + wn * (TNW * 16) + tn * 16 + ln;
    const float bb = (c < Nreal) ? bias[c] : 0.f;
#pragma unroll
    for (int tm = 0; tm < TMW; tm++) {
#pragma unroll
      for (int reg = 0; reg < 4; reg++) {
        const int r = row0 + wm * (TMW * 16) + tm * 16 + qd * 4 + reg;
        float v = acc[tm][tn][reg] + bb;
        if (EPI == EPI_RELU) v = fmaxf(v, 0.f);
        if (EPI == EPI_SIGMOID) v = 1.f / (1.f + __expf(-v));
        if (OMODE == 0) {
          Cf[(long)r * N + c] = v;
        } else if (OMODE == 1) {
          unsigned short h = f2bf(v);
          Ohi[(long)r * N + c] = h;
          Omid[(long)r * N + c] = f2bf(v - bf2f(h));
        } else {  // OMODE == 3: hi only
          Ohi[(long)r * N + c] = f2bf(v);
        }
      }
    }
  }
}

// dist candidates: grid (M/128 rows, 4 groups); block sweeps 512 cols in 4
// chunks of 128. Grid-x = row-block => XCD = rowblock%8: codebook strips stay
// L2-resident per XCD. Branchless packed-key top-3, one cross-lane merge.
__global__ __launch_bounds__(256, 2) void dist_topk(
    const unsigned short* __restrict__ Zh, const unsigned short* __restrict__ Zm,
    const unsigned short* __restrict__ Eh, const unsigned short* __restrict__ Em,
    const float* __restrict__ enorm, int* __restrict__ pidx, int M) {
  const int K = 256;
  __shared__ __align__(16) unsigned short Ah[128][BK], Am[128][BK];
  __shared__ __align__(16) unsigned short Bh[128][BK], Bm[128][BK];
  __shared__ unsigned r1s[2][128], r2s[2][128], r3s[2][128];

  const int tid = threadIdx.x, lane = tid & 63, wave = tid >> 6;
  const int wm = wave >> 1, wn = wave & 1;
  const int row0 = blockIdx.x * 128;
  const int col_base = blockIdx.y * 512;
  const int kshort = (lane & 3) * 8;

  const unsigned short *aH[2], *aM2[2];
  int rlj[2];
#pragma unroll
  for (int j = 0; j < 2; j++) {
    rlj[j] = (wave * 2 + j) * 16 + (lane >> 2);
    aH[j] = Zh + (long)(row0 + rlj[j]) * K + kshort;
    aM2[j] = Zm + (long)(row0 + rlj[j]) * K + kshort;
  }

  unsigned k1[16], k2[16], k3[16];
#pragma unroll
  for (int s = 0; s < 16; s++) { k1[s] = 0xFFFFFFFFu; k2[s] = 0xFFFFFFFFu; k3[s] = 0xFFFFFFFFu; }

  for (int ch = 0; ch < 4; ch++) {
    const int col0 = col_base + ch * 128;
    floatx4 acc[4][4];
#pragma unroll
    for (int i = 0; i < 4; i++)
#pragma unroll
      for (int j = 0; j < 4; j++) acc[i][j] = (floatx4)0.f;

    for (int k0 = 0; k0 < K; k0 += BK) {
      __syncthreads();
#pragma unroll
      for (int j = 0; j < 2; j++) {
        const int slot = wave * 2 + j;
        glds16(aH[j] + k0, &Ah[0][0] + slot * 512);
        glds16(aM2[j] + k0, &Am[0][0] + slot * 512);
        glds16(Eh + (long)(col0 + rlj[j]) * K + kshort + k0, &Bh[0][0] + slot * 512);
        glds16(Em + (long)(col0 + rlj[j]) * K + kshort + k0, &Bm[0][0] + slot * 512);
      }
      __syncthreads();

      short8 ah[4], am[4];
#pragma unroll
      for (int tm = 0; tm < 4; tm++) {
        const int rr = wm * 64 + tm * 16 + (lane & 15);
        const int kk = (lane >> 4) * 8;
        ah[tm] = *(const short8*)&Ah[rr][kk];
        am[tm] = *(const short8*)&Am[rr][kk];
      }
#pragma unroll
      for (int tn = 0; tn < 4; tn++) {
        const int rr = wn * 64 + tn * 16 + (lane & 15);
        const int kk = (lane >> 4) * 8;
        short8 bh = *(const short8*)&Bh[rr][kk];
        short8 bm = *(const short8*)&Bm[rr][kk];
#pragma unroll
        for (int tm = 0; tm < 4; tm++) {
          acc[tm][tn] = __builtin_amdgcn_mfma_f32_16x16x32_bf16(ah[tm], bh, acc[tm][tn], 0, 0, 0);
          acc[tm][tn] = __builtin_amdgcn_mfma_f32_16x16x32_bf16(ah[tm], bm, acc[tm][tn], 0, 0, 0);
          acc[tm][tn] = __builtin_amdgcn_mfma_f32_16x16x32_bf16(am[tm], bh, acc[tm][tn], 0, 0, 0);
        }
      }
    }

#pragma unroll
    for (int tn = 0; tn < 4; tn++) {
      const int c = col0 + wn * 64 + tn * 16 + (lane & 15);
      const float en = enorm[c];
#pragma unroll
      for (int tm = 0; tm < 4; tm++)
#pragma unroll
        for (int reg = 0; reg < 4; reg++) {
          float d = en - 2.f * acc[tm][tn][reg];
          ins3(packkey(d, c), k1[tm * 4 + reg], k2[tm * 4 + reg], k3[tm * 4 + reg]);
        }
    }
  }

#pragma unroll
  for (int s = 0; s < 16; s++) {
#pragma unroll
    for (int off = 1; off < 16; off <<= 1) {
      unsigned o1 = __shfl_xor(k1[s], off, 64);
      unsigned o2 = __shfl_xor(k2[s], off, 64);
      unsigned o3 = __shfl_xor(k3[s], off, 64);
      ins3(o1, k1[s], k2[s], k3[s]);
      ins3(o2, k1[s], k2[s], k3[s]);
      ins3(o3, k1[s], k2[s], k3[s]);
    }
  }
  if ((lane & 15) == 0) {
#pragma unroll
    for (int s = 0; s < 16; s++) {
      int rl = wm * 64 + (s >> 2) * 16 + (lane >> 4) * 4 + (s & 3);
      r1s[wn][rl] = k1[s]; r2s[wn][rl] = k2[s]; r3s[wn][rl] = k3[s];
    }
  }
  __syncthreads();
  if (tid < 128) {
    unsigned v1 = r1s[0][tid], v2 = r2s[0][tid], v3 = r3s[0][tid];
    ins3(r1s[1][tid], v1, v2, v3);
    ins3(r2s[1][tid], v1, v2, v3);
    ins3(r3s[1][tid], v1, v2, v3);
    const long base = ((long)blockIdx.y * M + (row0 + tid)) * 4;
    pidx[base + 0] = (int)(v1 & 0x7FFu);
    pidx[base + 1] = (int)(v2 & 0x7FFu);
    pidx[base + 2] = (int)(v3 & 0x7FFu);
  }
}

// exact fp32 rescore of 12 candidates/row; z = hi + mid (bit-identical to the
// value the dist kernel scored). One wave per row.
__global__ __launch_bounds__(256) void rescore(
    const unsigned short* __restrict__ zh, const unsigned short* __restrict__ zm,
    const float* __restrict__ emb, const float* __restrict__ enorm,
    const int* __restrict__ pidx, int* __restrict__ idx, int M) {
  const int wave = threadIdx.x >> 6, lane = threadIdx.x & 63;
  const int r = blockIdx.x * 4 + wave;
  ushort4v hz = *(const ushort4v*)(zh + (long)r * 256 + lane * 4);
  ushort4v mz = *(const ushort4v*)(zm + (long)r * 256 + lane * 4);
  float4 zv;
  zv.x = bf2f(hz.x) + bf2f(mz.x);
  zv.y = bf2f(hz.y) + bf2f(mz.y);
  zv.z = bf2f(hz.z) + bf2f(mz.z);
  zv.w = bf2f(hz.w) + bf2f(mz.w);
  float best = FLT_MAX;
  int bi = 0x7fffffff;
  for (int g = 0; g < 4; g++) {
#pragma unroll
    for (int s = 0; s < 3; s++) {
      const int j = pidx[((long)g * M + r) * 4 + s];
      float4 ev = *(const float4*)(emb + (long)j * 256 + lane * 4);
      float t = zv.x * ev.x + zv.y * ev.y + zv.z * ev.z + zv.w * ev.w;
#pragma unroll
      for (int off = 1; off < 64; off <<= 1) t += __shfl_xor(t, off, 64);
      const float d = enorm[j] - 2.f * t;
      if (d < best || (d == best && j < bi)) { best = d; bi = j; }
    }
  }
  if (lane == 0) idx[r] = bi;
}

extern "C" void kernel_launch(void* const* d_in, const int* in_sizes, int n_in,
                              void* d_out, int out_size, void* d_ws, size_t ws_size,
                              hipStream_t stream) {
  const float* x   = (const float*)d_in[0];
  const float* W1  = (const float*)d_in[1];
  const float* b1  = (const float*)d_in[2];
  const float* W2  = (const float*)d_in[3];
  const float* b2  = (const float*)d_in[4];
  const float* W3  = (const float*)d_in[5];
  const float* b3  = (const float*)d_in[6];
  const float* W4  = (const float*)d_in[7];
  const float* b4  = (const float*)d_in[8];
  const float* emb = (const float*)d_in[9];
  float* out = (float*)d_out;

  const int BZ = 16384, IN = 1024, H = 400, Hp = 512, D = 256;

  char* ws = (char*)d_ws;
  size_t off = 0;
  auto alloc = [&](size_t bytes) {
    void* p = ws + off;
    off += (bytes + 255) & ~(size_t)255;
    return p;
  };
  unsigned short* w1h = (unsigned short*)alloc((size_t)Hp * IN * 2);
  unsigned short* w1m = (unsigned short*)alloc((size_t)Hp * IN * 2);
  unsigned short* w2h = (unsigned short*)alloc((size_t)D * Hp * 2);
  unsigned short* w2m = (unsigned short*)alloc((size_t)D * Hp * 2);
  unsigned short* w3h = (unsigned short*)alloc((size_t)Hp * D * 2);
  unsigned short* w3m = (unsigned short*)alloc((size_t)Hp * D * 2);
  unsigned short* w4h = (unsigned short*)alloc((size_t)IN * Hp * 2);
  unsigned short* w4m = (unsigned short*)alloc((size_t)IN * Hp * 2);
  unsigned short* eh  = (unsigned short*)alloc((size_t)2048 * D * 2);
  unsigned short* em  = (unsigned short*)alloc((size_t)2048 * D * 2);
  float* enorm = (float*)alloc((size_t)2048 * 4);
  unsigned short* h1h = (unsigned short*)alloc((size_t)BZ * Hp * 2);  // 16MB
  unsigned short* h1m = (unsigned short*)alloc((size_t)BZ * Hp * 2);  // 16MB
  unsigned short* zh  = (unsigned short*)alloc((size_t)BZ * D * 2);   // 8MB
  unsigned short* zm  = (unsigned short*)alloc((size_t)BZ * D * 2);   // 8MB
  // aliases (lifetimes disjoint on the sequential stream):
  int* pidx = (int*)h1h;                       // h1 dead after GEMM2 (1MB used)
  int* idx  = ((int*)h1h) + (size_t)4 * BZ * 4;
  unsigned short* h3h = h1m;                   // h1m dead after GEMM2 (16MB)

  // fused prep: all weight/codebook conversions + emb norms in one dispatch
  prep<<<dim3(7680), dim3(256), 0, stream>>>(
      W1, w1h, w1m, W2, w2h, w2m, W3, w3h, w3m, W4, w4h, w4m, emb, eh, em, enorm);

  // h1 = relu(x @ W1^T + b1) -> hi/mid [BZ][512]   (bf16x3, 128x128, 512 blocks)
  mfma_gemm<EPI_RELU, false, false, 1, 4, 4, 3><<<dim3(Hp / 128, BZ / 128), dim3(256), 0, stream>>>(
      x, nullptr, nullptr, w1h, w1m, b1, nullptr, h1h, h1m, nullptr, BZ, Hp, IN, H);
  // z = h1 @ W2^T + b2 -> hi/mid [BZ][256]   (bf16x3, 64x128, 512 blocks)
  mfma_gemm<EPI_NONE, false, true, 1, 2, 4, 3><<<dim3(D / 128, BZ / 64), dim3(256), 0, stream>>>(
      nullptr, h1h, h1m, w2h, w2m, b2, nullptr, zh, zm, nullptr, BZ, D, Hp, D);
  // dist candidates: top-3 per 512-col group (XCD-affine grid), bf16x3
  dist_topk<<<dim3(BZ / 128, 4), dim3(256), 0, stream>>>(zh, zm, eh, em, enorm, pidx, BZ);
  // exact fp32 rescore of 12 -> idx
  rescore<<<dim3(BZ / 4), dim3(256), 0, stream>>>(zh, zm, emb, enorm, pidx, idx, BZ);
  // h3 = relu(emb[idx] @ W3^T + b3) -> bf16 hi only  (bf16x2 decoder, 512 blocks)
  mfma_gemm<EPI_RELU, true, true, 3, 4, 4, 2><<<dim3(Hp / 128, BZ / 128), dim3(256), 0, stream>>>(
      nullptr, eh, nullptr, w3h, w3m, b3, nullptr, h3h, nullptr, idx, BZ, Hp, D, H);
  // out = sigmoid(h3 @ W4^T + b4) -> fp32 [BZ][1024]  (bf16x2, 1024 blocks)
  mfma_gemm<EPI_SIGMOID, false, true, 0, 4, 4, 2><<<dim3(IN / 128, BZ / 128), dim3(256), 0, stream>>>(
      nullptr, h3h, nullptr, w4h, w4m, b4, out, nullptr, nullptr, nullptr, BZ, IN, Hp, IN);
}

// Round 11
// 330.459 us; speedup vs baseline: 1.0635x; 1.0140x over previous
//
#include <hip/hip_runtime.h>
#include <math.h>
#include <float.h>

// VQVAE forward, MI355X. Round 11: R10 + LDS-staged coalesced epilogue for
// bf16 outputs (fixes 2x write amplification + write-allocate refetch seen in
// GEMM1 counters: WRITE 65.6MB vs ideal 32, FETCH 133 vs ideal 69).
// Encoder/argmin bf16x3 (hi/mid RNE split), decoder bf16x2. dist: XCD-affine
// top-3 per 512-col group + exact fp32 rescore of 12 candidates.

typedef __attribute__((ext_vector_type(8))) short short8;      // MFMA A/B frag
typedef __attribute__((ext_vector_type(4))) float floatx4;     // MFMA C/D frag
typedef __attribute__((ext_vector_type(4))) unsigned short ushort4v;
typedef __attribute__((ext_vector_type(8))) unsigned short ushort8v;

__device__ __forceinline__ unsigned short f2bf(float f) {
  union { float f; unsigned u; } v; v.f = f;
  unsigned u = v.u;
  return (unsigned short)((u + 0x7FFFu + ((u >> 16) & 1u)) >> 16);
}
__device__ __forceinline__ float bf2f(unsigned short s) {
  union { unsigned u; float f; } v; v.u = ((unsigned)s) << 16;
  return v.f;
}

__device__ __forceinline__ void glds16(const void* g, void* l) {
  __builtin_amdgcn_global_load_lds(
      (const __attribute__((address_space(1))) unsigned int*)g,
      (__attribute__((address_space(3))) unsigned int*)l, 16, 0, 0);
}

__device__ __forceinline__ unsigned packkey(float d, int c) {
  unsigned b = __float_as_uint(d);
  b = (b & 0x80000000u) ? ~b : (b | 0x80000000u);
  return (b & 0xFFFFF800u) | (unsigned)c;
}
__device__ __forceinline__ void ins3(unsigned k, unsigned& v1, unsigned& v2,
                                     unsigned& v3) {
  unsigned t1 = min(v1, k), c1 = max(v1, k);
  unsigned t2 = min(v2, c1), c2 = max(v2, c1);
  v1 = t1; v2 = t2; v3 = min(v3, c2);
}

// one fp32->hi/mid padded conversion element; Cp compile-time (shifts)
template <int Cp>
__device__ __forceinline__ void conv_one(
    const float* __restrict__ src, unsigned short* __restrict__ hi,
    unsigned short* __restrict__ mid, int R, int C, int b) {
  const int t = b * 256 + (int)threadIdx.x;
  const int r = t / Cp, c = t & (Cp - 1);
  float v = (r < R && c < C) ? src[(long)r * C + c] : 0.f;
  unsigned short h = f2bf(v);
  hi[t] = h;
  mid[t] = f2bf(v - bf2f(h));
}

// fused prep: regions (block counts): W1 2048 | W2 512 | W3 512 | W4 2048 |
// emb 2048 | enorm 512. Grid = 7680 blocks.
__global__ __launch_bounds__(256) void prep(
    const float* __restrict__ W1, unsigned short* __restrict__ w1h, unsigned short* __restrict__ w1m,
    const float* __restrict__ W2, unsigned short* __restrict__ w2h, unsigned short* __restrict__ w2m,
    const float* __restrict__ W3, unsigned short* __restrict__ w3h, unsigned short* __restrict__ w3m,
    const float* __restrict__ W4, unsigned short* __restrict__ w4h, unsigned short* __restrict__ w4m,
    const float* __restrict__ emb, unsigned short* __restrict__ eh, unsigned short* __restrict__ em,
    float* __restrict__ enorm) {
  int b = blockIdx.x;
  if (b < 2048) {                       // W1: 400x1024 -> 512x1024
    conv_one<1024>(W1, w1h, w1m, 400, 1024, b);
  } else if (b < 2560) {                // W2: 256x400 -> 256x512
    conv_one<512>(W2, w2h, w2m, 256, 400, b - 2048);
  } else if (b < 3072) {                // W3: 400x256 -> 512x256
    conv_one<256>(W3, w3h, w3m, 400, 256, b - 2560);
  } else if (b < 5120) {                // W4: 1024x400 -> 1024x512
    conv_one<512>(W4, w4h, w4m, 1024, 400, b - 3072);
  } else if (b < 7168) {                // emb: 2048x256 -> 2048x256
    conv_one<256>(emb, eh, em, 2048, 256, b - 5120);
  } else {                              // enorm: 4 rows/block, 1 wave/row
    const int gtid = (b - 7168) * 256 + (int)threadIdx.x;
    const int j = gtid >> 6;
    const int lane = threadIdx.x & 63;
    float4 v = *(const float4*)(emb + (long)j * 256 + (lane << 2));
    float s = v.x * v.x + v.y * v.y + v.z * v.z + v.w * v.w;
#pragma unroll
    for (int off = 1; off < 64; off <<= 1) s += __shfl_xor(s, off, 64);
    if (lane == 0) enorm[j] = s;
  }
}

#define BK 32

enum { EPI_NONE = 0, EPI_RELU = 1, EPI_SIGMOID = 2 };
// OMODE: 0 = fp32 out, 1 = hi/mid split out, 3 = hi-only bf16 out
// NPROD: 3 = ah*bh + ah*bm + am*bh (fp32-grade); 2 = ah*bh + ah*bm (A hi-only)
// Wave grid 2x2; wave tile (TMW*16) x (TNW*16); BM = TMW*32, BN = TNW*32.

template <int EPI, bool INDIRECT, bool ASPLIT, int OMODE, int TMW, int TNW, int NPROD>
__global__ __launch_bounds__(256, 3) void mfma_gemm(
    const float* __restrict__ Af, const unsigned short* __restrict__ Ahg,
    const unsigned short* __restrict__ Amg, const unsigned short* __restrict__ Bhi,
    const unsigned short* __restrict__ Bmid, const float* __restrict__ bias,
    float* __restrict__ Cf, unsigned short* __restrict__ Ohi,
    unsigned short* __restrict__ Omid, const int* __restrict__ aidx,
    int M, int N, int K, int Nreal) {
  constexpr int BM = TMW * 32;
  constexpr int BN = TNW * 32;
  constexpr int ASW = BM / 64;    // A 16-row slots per wave per array
  constexpr int BSW = BN / 64;    // B 16-row slots per wave per array
  constexpr int ACELL = BM / 32;  // fp32-A staging cells
  __shared__ __align__(16) unsigned short Ah[BM][BK];
  __shared__ __align__(16) unsigned short Am[(NPROD == 3) ? BM : 1][BK];
  __shared__ __align__(16) unsigned short Bh[BN][BK], Bm[BN][BK];
  // coalescing stage for bf16 epilogues (re-used for hi then mid pass)
  __shared__ __align__(16) unsigned short OutS[(OMODE == 0) ? 1 : BM][BN + 8];

  const int tid = threadIdx.x, lane = tid & 63, wave = tid >> 6;
  const int wm = wave >> 1, wn = wave & 1;
  const int row0 = blockIdx.y * BM, col0 = blockIdx.x * BN;
  const int kshort = (lane & 3) * 8;

  const unsigned short *aH[ASW], *aM2[ASW], *bH[BSW], *bM2[BSW];
  const float* aF[ACELL];
  if (ASPLIT) {
#pragma unroll
    for (int j = 0; j < ASW; j++) {
      const int rl = (wave * ASW + j) * 16 + (lane >> 2);
      const long ar = INDIRECT ? (long)aidx[row0 + rl] : (long)(row0 + rl);
      aH[j] = Ahg + ar * K + kshort;
      if (NPROD == 3) aM2[j] = Amg + ar * K + kshort;
    }
  } else {
#pragma unroll
    for (int i = 0; i < ACELL; i++)
      aF[i] = Af + (long)(row0 + i * 32 + (tid >> 3)) * K + (tid & 7) * 4;
  }
#pragma unroll
  for (int j = 0; j < BSW; j++) {
    const int rl = (wave * BSW + j) * 16 + (lane >> 2);
    bH[j] = Bhi + (long)(col0 + rl) * K + kshort;
    bM2[j] = Bmid + (long)(col0 + rl) * K + kshort;
  }

  floatx4 acc[TMW][TNW];
#pragma unroll
  for (int i = 0; i < TMW; i++)
#pragma unroll
    for (int j = 0; j < TNW; j++) acc[i][j] = (floatx4)0.f;

  for (int k0 = 0; k0 < K; k0 += BK) {
    float4 areg[ACELL];
    if (!ASPLIT) {
#pragma unroll
      for (int i = 0; i < ACELL; i++) areg[i] = *(const float4*)(aF[i] + k0);
    }
    __syncthreads();  // prev-iter LDS reads complete
#pragma unroll
    for (int j = 0; j < BSW; j++) {
      const int slot = wave * BSW + j;
      glds16(bH[j] + k0, &Bh[0][0] + slot * 512);
      glds16(bM2[j] + k0, &Bm[0][0] + slot * 512);
    }
    if (ASPLIT) {
#pragma unroll
      for (int j = 0; j < ASW; j++) {
        const int slot = wave * ASW + j;
        glds16(aH[j] + k0, &Ah[0][0] + slot * 512);
        if (NPROD == 3) glds16(aM2[j] + k0, &Am[0][0] + slot * 512);
      }
    } else {
#pragma unroll
      for (int i = 0; i < ACELL; i++) {
        const int r = i * 32 + (tid >> 3), q4 = (tid & 7) * 4;
        ushort4v h, m;
        h.x = f2bf(areg[i].x); m.x = f2bf(areg[i].x - bf2f(h.x));
        h.y = f2bf(areg[i].y); m.y = f2bf(areg[i].y - bf2f(h.y));
        h.z = f2bf(areg[i].z); m.z = f2bf(areg[i].z - bf2f(h.z));
        h.w = f2bf(areg[i].w); m.w = f2bf(areg[i].w - bf2f(h.w));
        *(ushort4v*)&Ah[r][q4] = h;
        *(ushort4v*)&Am[r][q4] = m;
      }
    }
    __syncthreads();  // staging published

    short8 ah[TMW], am[TMW];
#pragma unroll
    for (int tm = 0; tm < TMW; tm++) {
      const int rr = wm * (TMW * 16) + tm * 16 + (lane & 15);
      const int kk = (lane >> 4) * 8;
      ah[tm] = *(const short8*)&Ah[rr][kk];
      if (NPROD == 3) am[tm] = *(const short8*)&Am[rr][kk];
    }
#pragma unroll
    for (int tn = 0; tn < TNW; tn++) {
      const int rr = wn * (TNW * 16) + tn * 16 + (lane & 15);
      const int kk = (lane >> 4) * 8;
      short8 bh = *(const short8*)&Bh[rr][kk];
      short8 bm = *(const short8*)&Bm[rr][kk];
#pragma unroll
      for (int tm = 0; tm < TMW; tm++) {
        acc[tm][tn] = __builtin_amdgcn_mfma_f32_16x16x32_bf16(ah[tm], bh, acc[tm][tn], 0, 0, 0);
        acc[tm][tn] = __builtin_amdgcn_mfma_f32_16x16x32_bf16(ah[tm], bm, acc[tm][tn], 0, 0, 0);
        if (NPROD == 3)
          acc[tm][tn] = __builtin_amdgcn_mfma_f32_16x16x32_bf16(am[tm], bh, acc[tm][tn], 0, 0, 0);
      }
    }
  }

  // C/D layout: col = lane&15, row = (lane>>4)*4 + reg
  const int qd = lane >> 4, ln = lane & 15;
  if (OMODE == 0) {
#pragma unroll
    for (int tn = 0; tn < TNW; tn++) {
      const int c = col0 + wn * (TNW * 16) + tn * 16 + ln;
      const float bb = (c < Nreal) ? bias[c] : 0.f;
#pragma unroll
      for (int tm = 0; tm < TMW; tm++) {
#pragma unroll
        for (int reg = 0; reg < 4; reg++) {
          const int r = row0 + wm * (TMW * 16) + tm * 16 + qd * 4 + reg;
          float v = acc[tm][tn][reg] + bb;
          if (EPI == EPI_RELU) v = fmaxf(v, 0.f);
          if (EPI == EPI_SIGMOID) v = 1.f / (1.f + __expf(-v));
          Cf[(long)r * N + c] = v;
        }
      }
    }
  } else {
    // staged bf16 epilogue: full-cache-line coalesced writes.
    float bbv[TNW];
#pragma unroll
    for (int tn = 0; tn < TNW; tn++) {
      const int c = col0 + wn * (TNW * 16) + tn * 16 + ln;
      bbv[tn] = (c < Nreal) ? bias[c] : 0.f;
    }
    constexpr int CPR = BN / 8;                // 16B chunks per row
    constexpr int NCH = (BM * BN) / (256 * 8); // chunks per thread
    // pass 1: hi
#pragma unroll
    for (int tn = 0; tn < TNW; tn++) {
      const int cl = wn * (TNW * 16) + tn * 16 + ln;
#pragma unroll
      for (int tm = 0; tm < TMW; tm++) {
#pragma unroll
        for (int reg = 0; reg < 4; reg++) {
          const int rl = wm * (TMW * 16) + tm * 16 + qd * 4 + reg;
          float v = acc[tm][tn][reg] + bbv[tn];
          if (EPI == EPI_RELU) v = fmaxf(v, 0.f);
          if (EPI == EPI_SIGMOID) v = 1.f / (1.f + __expf(-v));
          OutS[rl][cl] = f2bf(v);
        }
      }
    }
    __syncthreads();
#pragma unroll
    for (int i = 0; i < NCH; i++) {
      const int g = tid + 256 * i;
      const int row = g / CPR, cc = g % CPR;
      ushort8v val = *(const ushort8v*)&OutS[row][cc * 8];
      *(ushort8v*)(Ohi + (long)(row0 + row) * N + col0 + cc * 8) = val;
    }
    if (OMODE == 1) {
      __syncthreads();
      // pass 2: mid
#pragma unroll
      for (int tn = 0; tn < TNW; tn++) {
        const int cl = wn * (TNW * 16) + tn * 16 + ln;
#pragma unroll
        for (int tm = 0; tm < TMW; tm++) {
#pragma unroll
          for (int reg = 0; reg < 4; reg++) {
            const int rl = wm * (TMW * 16) + tm * 16 + qd * 4 + reg;
            float v = acc[tm][tn][reg] + bbv[tn];
            if (EPI == EPI_RELU) v = fmaxf(v, 0.f);
            if (EPI == EPI_SIGMOID) v = 1.f / (1.f + __expf(-v));
            unsigned short h = f2bf(v);
            OutS[rl][cl] = f2bf(v - bf2f(h));
          }
        }
      }
      __syncthreads();
#pragma unroll
      for (int i = 0; i < NCH; i++) {
        const int g = tid + 256 * i;
        const int row = g / CPR, cc = g % CPR;
        ushort8v val = *(const ushort8v*)&OutS[row][cc * 8];
        *(ushort8v*)(Omid + (long)(row0 + row) * N + col0 + cc * 8) = val;
      }
    }
  }
}

// dist candidates: grid (M/128 rows, 4 groups); block sweeps 512 cols in 4
// chunks of 128. Grid-x = row-block => XCD = rowblock%8: codebook strips stay
// L2-resident per XCD. Branchless packed-key top-3, one cross-lane merge.
__global__ __launch_bounds__(256, 2) void dist_topk(
    const unsigned short* __restrict__ Zh, const unsigned short* __restrict__ Zm,
    const unsigned short* __restrict__ Eh, const unsigned short* __restrict__ Em,
    const float* __restrict__ enorm, int* __restrict__ pidx, int M) {
  const int K = 256;
  __shared__ __align__(16) unsigned short Ah[128][BK], Am[128][BK];
  __shared__ __align__(16) unsigned short Bh[128][BK], Bm[128][BK];
  __shared__ unsigned r1s[2][128], r2s[2][128], r3s[2][128];

  const int tid = threadIdx.x, lane = tid & 63, wave = tid >> 6;
  const int wm = wave >> 1, wn = wave & 1;
  const int row0 = blockIdx.x * 128;
  const int col_base = blockIdx.y * 512;
  const int kshort = (lane & 3) * 8;

  const unsigned short *aH[2], *aM2[2];
  int rlj[2];
#pragma unroll
  for (int j = 0; j < 2; j++) {
    rlj[j] = (wave * 2 + j) * 16 + (lane >> 2);
    aH[j] = Zh + (long)(row0 + rlj[j]) * K + kshort;
    aM2[j] = Zm + (long)(row0 + rlj[j]) * K + kshort;
  }

  unsigned k1[16], k2[16], k3[16];
#pragma unroll
  for (int s = 0; s < 16; s++) { k1[s] = 0xFFFFFFFFu; k2[s] = 0xFFFFFFFFu; k3[s] = 0xFFFFFFFFu; }

  for (int ch = 0; ch < 4; ch++) {
    const int col0 = col_base + ch * 128;
    floatx4 acc[4][4];
#pragma unroll
    for (int i = 0; i < 4; i++)
#pragma unroll
      for (int j = 0; j < 4; j++) acc[i][j] = (floatx4)0.f;

    for (int k0 = 0; k0 < K; k0 += BK) {
      __syncthreads();
#pragma unroll
      for (int j = 0; j < 2; j++) {
        const int slot = wave * 2 + j;
        glds16(aH[j] + k0, &Ah[0][0] + slot * 512);
        glds16(aM2[j] + k0, &Am[0][0] + slot * 512);
        glds16(Eh + (long)(col0 + rlj[j]) * K + kshort + k0, &Bh[0][0] + slot * 512);
        glds16(Em + (long)(col0 + rlj[j]) * K + kshort + k0, &Bm[0][0] + slot * 512);
      }
      __syncthreads();

      short8 ah[4], am[4];
#pragma unroll
      for (int tm = 0; tm < 4; tm++) {
        const int rr = wm * 64 + tm * 16 + (lane & 15);
        const int kk = (lane >> 4) * 8;
        ah[tm] = *(const short8*)&Ah[rr][kk];
        am[tm] = *(const short8*)&Am[rr][kk];
      }
#pragma unroll
      for (int tn = 0; tn < 4; tn++) {
        const int rr = wn * 64 + tn * 16 + (lane & 15);
        const int kk = (lane >> 4) * 8;
        short8 bh = *(const short8*)&Bh[rr][kk];
        short8 bm = *(const short8*)&Bm[rr][kk];
#pragma unroll
        for (int tm = 0; tm < 4; tm++) {
          acc[tm][tn] = __builtin_amdgcn_mfma_f32_16x16x32_bf16(ah[tm], bh, acc[tm][tn], 0, 0, 0);
          acc[tm][tn] = __builtin_amdgcn_mfma_f32_16x16x32_bf16(ah[tm], bm, acc[tm][tn], 0, 0, 0);
          acc[tm][tn] = __builtin_amdgcn_mfma_f32_16x16x32_bf16(am[tm], bh, acc[tm][tn], 0, 0, 0);
        }
      }
    }

#pragma unroll
    for (int tn = 0; tn < 4; tn++) {
      const int c = col0 + wn * 64 + tn * 16 + (lane & 15);
      const float en = enorm[c];
#pragma unroll
      for (int tm = 0; tm < 4; tm++)
#pragma unroll
        for (int reg = 0; reg < 4; reg++) {
          float d = en - 2.f * acc[tm][tn][reg];
          ins3(packkey(d, c), k1[tm * 4 + reg], k2[tm * 4 + reg], k3[tm * 4 + reg]);
        }
    }
  }

#pragma unroll
  for (int s = 0; s < 16; s++) {
#pragma unroll
    for (int off = 1; off < 16; off <<= 1) {
      unsigned o1 = __shfl_xor(k1[s], off, 64);
      unsigned o2 = __shfl_xor(k2[s], off, 64);
      unsigned o3 = __shfl_xor(k3[s], off, 64);
      ins3(o1, k1[s], k2[s], k3[s]);
      ins3(o2, k1[s], k2[s], k3[s]);
      ins3(o3, k1[s], k2[s], k3[s]);
    }
  }
  if ((lane & 15) == 0) {
#pragma unroll
    for (int s = 0; s < 16; s++) {
      int rl = wm * 64 + (s >> 2) * 16 + (lane >> 4) * 4 + (s & 3);
      r1s[wn][rl] = k1[s]; r2s[wn][rl] = k2[s]; r3s[wn][rl] = k3[s];
    }
  }
  __syncthreads();
  if (tid < 128) {
    unsigned v1 = r1s[0][tid], v2 = r2s[0][tid], v3 = r3s[0][tid];
    ins3(r1s[1][tid], v1, v2, v3);
    ins3(r2s[1][tid], v1, v2, v3);
    ins3(r3s[1][tid], v1, v2, v3);
    const long base = ((long)blockIdx.y * M + (row0 + tid)) * 4;
    pidx[base + 0] = (int)(v1 & 0x7FFu);
    pidx[base + 1] = (int)(v2 & 0x7FFu);
    pidx[base + 2] = (int)(v3 & 0x7FFu);
  }
}

// exact fp32 rescore of 12 candidates/row; z = hi + mid (bit-identical to the
// value the dist kernel scored). One wave per row.
__global__ __launch_bounds__(256) void rescore(
    const unsigned short* __restrict__ zh, const unsigned short* __restrict__ zm,
    const float* __restrict__ emb, const float* __restrict__ enorm,
    const int* __restrict__ pidx, int* __restrict__ idx, int M) {
  const int wave = threadIdx.x >> 6, lane = threadIdx.x & 63;
  const int r = blockIdx.x * 4 + wave;
  ushort4v hz = *(const ushort4v*)(zh + (long)r * 256 + lane * 4);
  ushort4v mz = *(const ushort4v*)(zm + (long)r * 256 + lane * 4);
  float4 zv;
  zv.x = bf2f(hz.x) + bf2f(mz.x);
  zv.y = bf2f(hz.y) + bf2f(mz.y);
  zv.z = bf2f(hz.z) + bf2f(mz.z);
  zv.w = bf2f(hz.w) + bf2f(mz.w);
  float best = FLT_MAX;
  int bi = 0x7fffffff;
  for (int g = 0; g < 4; g++) {
#pragma unroll
    for (int s = 0; s < 3; s++) {
      const int j = pidx[((long)g * M + r) * 4 + s];
      float4 ev = *(const float4*)(emb + (long)j * 256 + lane * 4);
      float t = zv.x * ev.x + zv.y * ev.y + zv.z * ev.z + zv.w * ev.w;
#pragma unroll
      for (int off = 1; off < 64; off <<= 1) t += __shfl_xor(t, off, 64);
      const float d = enorm[j] - 2.f * t;
      if (d < best || (d == best && j < bi)) { best = d; bi = j; }
    }
  }
  if (lane == 0) idx[r] = bi;
}

extern "C" void kernel_launch(void* const* d_in, const int* in_sizes, int n_in,
                              void* d_out, int out_size, void* d_ws, size_t ws_size,
                              hipStream_t stream) {
  const float* x   = (const float*)d_in[0];
  const float* W1  = (const float*)d_in[1];
  const float* b1  = (const float*)d_in[2];
  const float* W2  = (const float*)d_in[3];
  const float* b2  = (const float*)d_in[4];
  const float* W3  = (const float*)d_in[5];
  const float* b3  = (const float*)d_in[6];
  const float* W4  = (const float*)d_in[7];
  const float* b4  = (const float*)d_in[8];
  const float* emb = (const float*)d_in[9];
  float* out = (float*)d_out;

  const int BZ = 16384, IN = 1024, H = 400, Hp = 512, D = 256;

  char* ws = (char*)d_ws;
  size_t off = 0;
  auto alloc = [&](size_t bytes) {
    void* p = ws + off;
    off += (bytes + 255) & ~(size_t)255;
    return p;
  };
  unsigned short* w1h = (unsigned short*)alloc((size_t)Hp * IN * 2);
  unsigned short* w1m = (unsigned short*)alloc((size_t)Hp * IN * 2);
  unsigned short* w2h = (unsigned short*)alloc((size_t)D * Hp * 2);
  unsigned short* w2m = (unsigned short*)alloc((size_t)D * Hp * 2);
  unsigned short* w3h = (unsigned short*)alloc((size_t)Hp * D * 2);
  unsigned short* w3m = (unsigned short*)alloc((size_t)Hp * D * 2);
  unsigned short* w4h = (unsigned short*)alloc((size_t)IN * Hp * 2);
  unsigned short* w4m = (unsigned short*)alloc((size_t)IN * Hp * 2);
  unsigned short* eh  = (unsigned short*)alloc((size_t)2048 * D * 2);
  unsigned short* em  = (unsigned short*)alloc((size_t)2048 * D * 2);
  float* enorm = (float*)alloc((size_t)2048 * 4);
  unsigned short* h1h = (unsigned short*)alloc((size_t)BZ * Hp * 2);  // 16MB
  unsigned short* h1m = (unsigned short*)alloc((size_t)BZ * Hp * 2);  // 16MB
  unsigned short* zh  = (unsigned short*)alloc((size_t)BZ * D * 2);   // 8MB
  unsigned short* zm  = (unsigned short*)alloc((size_t)BZ * D * 2);   // 8MB
  // aliases (lifetimes disjoint on the sequential stream):
  int* pidx = (int*)h1h;                       // h1 dead after GEMM2 (1MB used)
  int* idx  = ((int*)h1h) + (size_t)4 * BZ * 4;
  unsigned short* h3h = h1m;                   // h1m dead after GEMM2 (16MB)

  // fused prep: all weight/codebook conversions + emb norms in one dispatch
  prep<<<dim3(7680), dim3(256), 0, stream>>>(
      W1, w1h, w1m, W2, w2h, w2m, W3, w3h, w3m, W4, w4h, w4m, emb, eh, em, enorm);

  // h1 = relu(x @ W1^T + b1) -> hi/mid [BZ][512]   (bf16x3, 128x128, 512 blocks)
  mfma_gemm<EPI_RELU, false, false, 1, 4, 4, 3><<<dim3(Hp / 128, BZ / 128), dim3(256), 0, stream>>>(
      x, nullptr, nullptr, w1h, w1m, b1, nullptr, h1h, h1m, nullptr, BZ, Hp, IN, H);
  // z = h1 @ W2^T + b2 -> hi/mid [BZ][256]   (bf16x3, 64x128, 512 blocks)
  mfma_gemm<EPI_NONE, false, true, 1, 2, 4, 3><<<dim3(D / 128, BZ / 64), dim3(256), 0, stream>>>(
      nullptr, h1h, h1m, w2h, w2m, b2, nullptr, zh, zm, nullptr, BZ, D, Hp, D);
  // dist candidates: top-3 per 512-col group (XCD-affine grid), bf16x3
  dist_topk<<<dim3(BZ / 128, 4), dim3(256), 0, stream>>>(zh, zm, eh, em, enorm, pidx, BZ);
  // exact fp32 rescore of 12 -> idx
  rescore<<<dim3(BZ / 4), dim3(256), 0, stream>>>(zh, zm, emb, enorm, pidx, idx, BZ);
  // h3 = relu(emb[idx] @ W3^T + b3) -> bf16 hi only  (bf16x2 decoder, 512 blocks)
  mfma_gemm<EPI_RELU, true, true, 3, 4, 4, 2><<<dim3(Hp / 128, BZ / 128), dim3(256), 0, stream>>>(
      nullptr, eh, nullptr, w3h, w3m, b3, nullptr, h3h, nullptr, idx, BZ, Hp, D, H);
  // out = sigmoid(h3 @ W4^T + b4) -> fp32 [BZ][1024]  (bf16x2, 1024 blocks)
  mfma_gemm<EPI_SIGMOID, false, true, 0, 4, 4, 2><<<dim3(IN / 128, BZ / 128), dim3(256), 0, stream>>>(
      nullptr, h3h, nullptr, w4h, w4m, b4, out, nullptr, nullptr, nullptr, BZ, IN, Hp, IN);
}